// Round 6
// baseline (108.403 us; speedup 1.0000x reference)
//
#include <hip/hip_runtime.h>
#include <math.h>

// Problem constants (reference: B=4, N=M=8192, D=3, fp32)
#define BQ     4
#define NPTS   8192
#define WG     256
#define CHUNK  256                // m-points staged in LDS per block
#define UA     8                  // a-points per thread (registers)
#define ABLK   (WG * UA)          // 2048 a-points per block
#define NCH    (NPTS / CHUNK)     // 32 m-chunks -> 1024 blocks = 4/CU
#define TOTALA (2 * BQ * NPTS)    // 65536 a-points across batch*dir

// d^2 = ||a||^2 + (||b||^2 - 2 a.b); b' = (-2bx,-2by,-2bz,||b||^2) in LDS.
// Inner: 3 fma per m-point + v_min3 over m-pairs. The empty asm pins each
// staged float4 in VGPRs (opaque value -> compiler cannot re-read LDS in a
// k-loop split, which is what produced the 28-VGPR / 2x-issue codegen).
__global__ __launch_bounds__(WG, 2) void chamfer_min_kernel(
    const float* __restrict__ yhat, const float* __restrict__ y,
    unsigned* __restrict__ part, float* __restrict__ scratch, int atomicPath) {
  if (blockIdx.x == 0 && blockIdx.y == 0 && blockIdx.z == 0 && threadIdx.x == 0) {
    scratch[0] = 0.f;
    ((unsigned*)scratch)[1] = 0u;
  }

  const int bz = blockIdx.z, b = bz >> 1, dir = bz & 1;
  const float* A  = (dir ? y    : yhat) + (size_t)b * NPTS * 3;
  const float* Bp = (dir ? yhat : y   ) + (size_t)b * NPTS * 3;

  __shared__ float4 bs[CHUNK];
  {
    const int i = threadIdx.x;  // CHUNK == WG: one point per thread
    const float* p = Bp + (size_t)(blockIdx.y * CHUNK + i) * 3;
    const float x = p[0], yv = p[1], z = p[2];
    bs[i] = make_float4(-2.f * x, -2.f * yv, -2.f * z,
                        fmaf(x, x, fmaf(yv, yv, z * z)));
  }

  const int nbase = blockIdx.x * ABLK + threadIdx.x;
  float ax[UA], ay[UA], az[UA], mn[UA];
#pragma unroll
  for (int k = 0; k < UA; ++k) {
    const float* p = A + (size_t)(nbase + k * WG) * 3;
    ax[k] = p[0]; ay[k] = p[1]; az[k] = p[2];
    mn[k] = 3.0e38f;
  }
  __syncthreads();

#pragma unroll 2
  for (int m = 0; m < CHUNK; m += 4) {
    float4 b0 = bs[m], b1 = bs[m + 1], b2 = bs[m + 2], b3 = bs[m + 3];
    asm("" : "+v"(b0.x), "+v"(b0.y), "+v"(b0.z), "+v"(b0.w),
             "+v"(b1.x), "+v"(b1.y), "+v"(b1.z), "+v"(b1.w),
             "+v"(b2.x), "+v"(b2.y), "+v"(b2.z), "+v"(b2.w),
             "+v"(b3.x), "+v"(b3.y), "+v"(b3.z), "+v"(b3.w));
#pragma unroll
    for (int k = 0; k < UA; ++k) {
      const float t0 = fmaf(ax[k], b0.x, fmaf(ay[k], b0.y, fmaf(az[k], b0.z, b0.w)));
      const float t1 = fmaf(ax[k], b1.x, fmaf(ay[k], b1.y, fmaf(az[k], b1.z, b1.w)));
      const float t2 = fmaf(ax[k], b2.x, fmaf(ay[k], b2.y, fmaf(az[k], b2.z, b2.w)));
      const float t3 = fmaf(ax[k], b3.x, fmaf(ay[k], b3.y, fmaf(az[k], b3.z, b3.w)));
      mn[k] = fminf(mn[k], fminf(t0, t1));  // v_min3_f32
      mn[k] = fminf(mn[k], fminf(t2, t3));  // v_min3_f32
    }
  }

  const int base = bz * NPTS + blockIdx.x * ABLK + threadIdx.x;
  if (atomicPath) {
#pragma unroll
    for (int k = 0; k < UA; ++k) {
      const float sq = fmaf(ax[k], ax[k], fmaf(ay[k], ay[k], az[k] * az[k]));
      const float d2 = fmaxf(sq + mn[k], 0.f);
      atomicMin(&part[base + k * WG], __float_as_uint(d2));
    }
  } else {
    unsigned* outp = part + (size_t)blockIdx.y * TOTALA;
#pragma unroll
    for (int k = 0; k < UA; ++k) {
      const float sq = fmaf(ax[k], ax[k], fmaf(ay[k], ay[k], az[k] * az[k]));
      const float d2 = fmaxf(sq + mn[k], 0.f);
      outp[base + k * WG] = __float_as_uint(d2);
    }
  }
}

// One j per thread; min across chunks (per-wave rotated order to spread the
// 256 KB power-of-2 stride), then sum -> atomicAdd -> last block sqrt+store.
__global__ __launch_bounds__(256) void chamfer_reduce_final_kernel(
    const unsigned* __restrict__ part, float* __restrict__ scratch,
    float* __restrict__ out, int nch) {
  const int j = blockIdx.x * 256 + threadIdx.x;  // 256 blocks -> 0..65535
  const int wave = threadIdx.x >> 6, lane = threadIdx.x & 63;
  const int rot = (blockIdx.x * 4 + wave) & (NCH - 1);
  float mv = 3.4e38f;
  if (nch == 1) {
    mv = __uint_as_float(part[j]);
  } else {
#pragma unroll
    for (int c = 0; c < NCH; ++c) {
      const int mc = (c + rot) & (NCH - 1);
      mv = fminf(mv, __uint_as_float(part[(size_t)mc * TOTALA + j]));
    }
  }
  float s = mv;
#pragma unroll
  for (int off = 32; off > 0; off >>= 1) s += __shfl_down(s, off, 64);
  __shared__ float p4[4];
  if (lane == 0) p4[wave] = s;
  __syncthreads();
  if (threadIdx.x == 0) {
    atomicAdd(&scratch[0], p4[0] + p4[1] + p4[2] + p4[3]);
    __threadfence();
    const unsigned ticket = atomicAdd(&((unsigned*)scratch)[1], 1u);
    if (ticket == gridDim.x - 1) {
      __threadfence();
      const float total = atomicAdd(&scratch[0], 0.f);  // atomic read
      out[0] = sqrtf(total * (1.0f / (float)TOTALA));
    }
  }
}

extern "C" void kernel_launch(void* const* d_in, const int* in_sizes, int n_in,
                              void* d_out, int out_size, void* d_ws, size_t ws_size,
                              hipStream_t stream) {
  const float* yhat = (const float*)d_in[0];
  const float* y    = (const float*)d_in[1];
  unsigned* part = (unsigned*)d_ws;

  const size_t needFull = ((size_t)NCH * TOTALA + 2) * sizeof(unsigned);
  const int atomicPath = ws_size < needFull;

  float* scratch;
  if (atomicPath) {
    // init to +big so atomicMin on float bits works (all d2 >= 0)
    hipMemsetAsync(part, 0x7F, (size_t)TOTALA * sizeof(unsigned), stream);
    scratch = (float*)(part + TOTALA);
  } else {
    scratch = (float*)(part + (size_t)NCH * TOTALA);
  }

  dim3 grid(NPTS / ABLK, NCH, 2 * BQ);
  chamfer_min_kernel<<<grid, WG, 0, stream>>>(yhat, y, part, scratch, atomicPath);
  chamfer_reduce_final_kernel<<<256, 256, 0, stream>>>(part, scratch, (float*)d_out,
                                                       atomicPath ? 1 : NCH);
}

// Round 7
// 106.810 us; speedup vs baseline: 1.0149x; 1.0149x over previous
//
#include <hip/hip_runtime.h>
#include <math.h>

// Problem constants (reference: B=4, N=M=8192, D=3, fp32)
#define BQ      4
#define NPTS    8192
#define NSETPTS (BQ * NPTS)        // 32768 points per input set
#define TOTALA  (2 * BQ * NPTS)    // 65536 (batch*dir rows)
#define MCHUNK  1024               // m-points staged in LDS per block
#define NCH     (NPTS / MCHUNK)    // 8 m-chunks

// ws byte offsets (total use: 6 MB + 8 B; proven ws_size >= 8.4 MB in R6)
#define OFF_A_YHAT 0u
#define OFF_B_YHAT (1u << 20)
#define OFF_A_Y    (2u << 20)
#define OFF_B_Y    (3u << 20)
#define OFF_PART   (4u << 20)      // float [NCH][TOTALA] = 2 MB
#define OFF_SCR    (6u << 20)      // accumulator + ticket

typedef __attribute__((ext_vector_type(8)))  short bf16x8;
typedef __attribute__((ext_vector_type(16))) float f32x16;

__device__ inline unsigned short f2bf(float f) {   // RNE float->bf16
  unsigned u = __float_as_uint(f);
  u += 0x7FFF + ((u >> 16) & 1);
  return (unsigned short)(u >> 16);
}
__device__ inline float bf2f(unsigned short h) {
  return __uint_as_float(((unsigned)h) << 16);
}
__device__ inline uint4 pack8(const unsigned short* e) {
  uint4 r;
  r.x = e[0] | ((unsigned)e[1] << 16);
  r.y = e[2] | ((unsigned)e[3] << 16);
  r.z = e[4] | ((unsigned)e[5] << 16);
  r.w = e[6] | ((unsigned)e[7] << 16);
  return r;
}

// Build per-point K=16 MFMA vectors (split-bf16 trick):
//   dot(Avec, Bvec) = ||a||^2 + ||b||^2 - 2 a.b + O(2^-18)
// A = [ahi3, ahi3, alo3, sqa_hi, sqa_lo, 1, 1, 0,0,0]
// B = [-2bhi3, -2blo3, -2bhi3, 1, 1, sqb_hi, sqb_lo, 0,0,0]
__global__ __launch_bounds__(256) void chamfer_prep_kernel(
    const float* __restrict__ yhat, const float* __restrict__ y,
    unsigned char* __restrict__ ws) {
  const int id = blockIdx.x * 256 + threadIdx.x;  // 0..65535
  if (id == 0) {  // zero the fused-reduce accumulator + ticket
    float* scr = (float*)(ws + OFF_SCR);
    scr[0] = 0.f;
    ((unsigned*)scr)[1] = 0u;
  }
  const int isY = id >= NSETPTS;
  const int pi = id & (NSETPTS - 1);
  const float* src = (isY ? y : yhat) + (size_t)pi * 3;
  const float x = src[0], yv = src[1], z = src[2];

  const unsigned short xh = f2bf(x),  yh = f2bf(yv), zh = f2bf(z);
  const unsigned short xl = f2bf(x - bf2f(xh));
  const unsigned short yl = f2bf(yv - bf2f(yh));
  const unsigned short zl = f2bf(z - bf2f(zh));
  const float sq = fmaf(x, x, fmaf(yv, yv, z * z));
  const unsigned short sh = f2bf(sq), sl = f2bf(sq - bf2f(sh));
  // -2*hi and -2*lo are exact bf16 scalings
  const unsigned short nxh = f2bf(-2.f * bf2f(xh)), nyh = f2bf(-2.f * bf2f(yh)),
                       nzh = f2bf(-2.f * bf2f(zh));
  const unsigned short nxl = f2bf(-2.f * bf2f(xl)), nyl = f2bf(-2.f * bf2f(yl)),
                       nzl = f2bf(-2.f * bf2f(zl));
  const unsigned short ONE = 0x3F80;

  const unsigned short av[16] = {xh, yh, zh, xh, yh, zh, xl, yl, zl,
                                 sh, sl, ONE, ONE, 0, 0, 0};
  const unsigned short bv[16] = {nxh, nyh, nzh, nxl, nyl, nzl, nxh, nyh, nzh,
                                 ONE, ONE, sh, sl, 0, 0, 0};
  uint4* Aout = (uint4*)(ws + (isY ? OFF_A_Y : OFF_A_YHAT)) + (size_t)pi * 2;
  uint4* Bout = (uint4*)(ws + (isY ? OFF_B_Y : OFF_B_YHAT)) + (size_t)pi * 2;
  Aout[0] = pack8(av);
  Aout[1] = pack8(av + 8);
  Bout[0] = pack8(bv);
  Bout[1] = pack8(bv + 8);
}

// One wave = one 32-row n-tile; block = 4 waves = 128 rows; loop 32-point
// m-tiles from a 1024-point LDS-staged chunk. One MFMA computes the whole
// 32x32 d^2 tile; 16 v_min3 fold it into the running min.
// A-frag: row=lane&31, k=8*(lane>>5)+j. B-frag: col=lane&31, same k.
// C/D (m74/m101, HW-verified): col=lane&31, row=(reg&3)+8*(reg>>2)+4*(lane>>5).
__global__ __launch_bounds__(256, 2) void chamfer_min_kernel(
    unsigned char* __restrict__ ws) {
  const int bz = blockIdx.z, b = bz >> 1, dir = bz & 1;
  const uint4* Avec = (const uint4*)(ws + (dir ? OFF_A_Y : OFF_A_YHAT)) +
                      (size_t)b * NPTS * 2;
  const uint4* Bvec = (const uint4*)(ws + (dir ? OFF_B_YHAT : OFF_B_Y)) +
                      (size_t)b * NPTS * 2;
  float* part = (float*)(ws + OFF_PART);

  __shared__ uint4 bs[2][MCHUNK];  // [k-half][point] 16B, 32 KB
  const int m0 = blockIdx.y * MCHUNK;
  for (int i = threadIdx.x; i < MCHUNK; i += 256) {
    bs[0][i] = Bvec[(size_t)(m0 + i) * 2];
    bs[1][i] = Bvec[(size_t)(m0 + i) * 2 + 1];
  }

  const int lane = threadIdx.x & 63, wave = threadIdx.x >> 6;
  const int h = lane >> 5, c = lane & 31;
  const int n0 = blockIdx.x * 128 + wave * 32;
  const uint4 araw = Avec[(size_t)(n0 + c) * 2 + h];
  const bf16x8 a8 = __builtin_bit_cast(bf16x8, araw);
  __syncthreads();

  float rm[16];
#pragma unroll
  for (int r = 0; r < 16; ++r) rm[r] = 3.0e38f;
  const f32x16 zacc = (f32x16)(0.0f);

  for (int t = 0; t < MCHUNK / 32; t += 2) {  // 2 independent MFMA chains
    const uint4 br0 = bs[h][t * 32 + c];
    const uint4 br1 = bs[h][(t + 1) * 32 + c];
    f32x16 acc0 = __builtin_amdgcn_mfma_f32_32x32x16_bf16(
        a8, __builtin_bit_cast(bf16x8, br0), zacc, 0, 0, 0);
    f32x16 acc1 = __builtin_amdgcn_mfma_f32_32x32x16_bf16(
        a8, __builtin_bit_cast(bf16x8, br1), zacc, 0, 0, 0);
#pragma unroll
    for (int r = 0; r < 16; ++r)
      rm[r] = fminf(rm[r], fminf(acc0[r], acc1[r]));  // v_min3_f32
  }

  // min over cols = butterfly across lanes 0..31 within each half
  // (xor masks <= 16 never cross the lane-bit-5 boundary)
#pragma unroll
  for (int r = 0; r < 16; ++r) {
    float v = rm[r];
    v = fminf(v, __shfl_xor(v, 1));
    v = fminf(v, __shfl_xor(v, 2));
    v = fminf(v, __shfl_xor(v, 4));
    v = fminf(v, __shfl_xor(v, 8));
    v = fminf(v, __shfl_xor(v, 16));
    rm[r] = v;
  }
  if (c == 0) {  // lanes 0 and 32 hold the 32 per-row minima
    float* outp = part + (size_t)blockIdx.y * TOTALA + bz * NPTS + n0;
#pragma unroll
    for (int r = 0; r < 16; ++r) {
      const int row = (r & 3) + 8 * (r >> 2) + 4 * h;
      outp[row] = rm[r];
    }
  }
}

// min across chunks (rotated order to spread the 256 KB stride), clamp,
// sum -> atomicAdd -> last block does sqrt + store.
__global__ __launch_bounds__(256) void chamfer_reduce_kernel(
    unsigned char* __restrict__ ws, float* __restrict__ out) {
  const float* part = (const float*)(ws + OFF_PART);
  float* scr = (float*)(ws + OFF_SCR);
  const int j = blockIdx.x * 256 + threadIdx.x;  // 0..65535
  const int wave = threadIdx.x >> 6, lane = threadIdx.x & 63;
  const int rot = (blockIdx.x * 4 + wave) & (NCH - 1);
  float mv = 3.4e38f;
#pragma unroll
  for (int cc = 0; cc < NCH; ++cc) {
    const int mc = (cc + rot) & (NCH - 1);
    mv = fminf(mv, part[(size_t)mc * TOTALA + j]);
  }
  mv = fmaxf(mv, 0.f);  // == per-element clamp then min (both sides >= 0)
  float s = mv;
#pragma unroll
  for (int off = 32; off > 0; off >>= 1) s += __shfl_down(s, off, 64);
  __shared__ float p4[4];
  if (lane == 0) p4[wave] = s;
  __syncthreads();
  if (threadIdx.x == 0) {
    atomicAdd(&scr[0], p4[0] + p4[1] + p4[2] + p4[3]);
    __threadfence();
    const unsigned ticket = atomicAdd(&((unsigned*)scr)[1], 1u);
    if (ticket == gridDim.x - 1) {
      __threadfence();
      const float total = atomicAdd(&scr[0], 0.f);  // atomic read
      out[0] = sqrtf(total * (1.0f / (float)TOTALA));
    }
  }
}

extern "C" void kernel_launch(void* const* d_in, const int* in_sizes, int n_in,
                              void* d_out, int out_size, void* d_ws, size_t ws_size,
                              hipStream_t stream) {
  const float* yhat = (const float*)d_in[0];
  const float* y    = (const float*)d_in[1];
  unsigned char* ws = (unsigned char*)d_ws;

  chamfer_prep_kernel<<<TOTALA / 256, 256, 0, stream>>>(yhat, y, ws);
  dim3 grid(NPTS / 128, NCH, 2 * BQ);
  chamfer_min_kernel<<<grid, 256, 0, stream>>>(ws);
  chamfer_reduce_kernel<<<256, 256, 0, stream>>>(ws, (float*)d_out);
}

// Round 8
// 98.834 us; speedup vs baseline: 1.0968x; 1.0807x over previous
//
#include <hip/hip_runtime.h>
#include <math.h>

// Problem constants (reference: B=4, N=M=8192, D=3, fp32)
#define BQ      4
#define NPTS    8192
#define NSETPTS (BQ * NPTS)        // 32768 points per input set
#define TOTALA  (2 * BQ * NPTS)    // 65536 (batch*dir rows)
#define MCHUNK  1024               // m-points staged in LDS per block
#define NCH     (NPTS / MCHUNK)    // 8 m-chunks

// ws byte offsets (total use: 6 MB + 8 B; ws_size >= 8 MB proven in R6)
#define OFF_A_YHAT 0u
#define OFF_B_YHAT (1u << 20)
#define OFF_A_Y    (2u << 20)
#define OFF_B_Y    (3u << 20)
#define OFF_PART   (4u << 20)      // unsigned [TOTALA] float-bits = 256 KB
#define OFF_SCR    (6u << 20)      // accumulator + ticket

typedef __attribute__((ext_vector_type(8)))  short bf16x8;
typedef __attribute__((ext_vector_type(16))) float f32x16;

__device__ inline unsigned short f2bf(float f) {   // RNE float->bf16
  unsigned u = __float_as_uint(f);
  u += 0x7FFF + ((u >> 16) & 1);
  return (unsigned short)(u >> 16);
}
__device__ inline float bf2f(unsigned short h) {
  return __uint_as_float(((unsigned)h) << 16);
}
__device__ inline uint4 pack8(const unsigned short* e) {
  uint4 r;
  r.x = e[0] | ((unsigned)e[1] << 16);
  r.y = e[2] | ((unsigned)e[3] << 16);
  r.z = e[4] | ((unsigned)e[5] << 16);
  r.w = e[6] | ((unsigned)e[7] << 16);
  return r;
}

// Build per-point K=16 MFMA vectors (split-bf16):
//   dot(Avec, Bvec) = ||a||^2 + ||b||^2 - 2 a.b + O(2^-18)
// Also init part[] to +big (atomicMin float-bits) and the scr accumulator.
__global__ __launch_bounds__(256) void chamfer_prep_kernel(
    const float* __restrict__ yhat, const float* __restrict__ y,
    unsigned char* __restrict__ ws) {
  const int id = blockIdx.x * 256 + threadIdx.x;  // 0..65535 == TOTALA
  ((unsigned*)(ws + OFF_PART))[id] = 0x7F7F7F7Fu;  // 3.39e38
  if (id == 0) {
    float* scr = (float*)(ws + OFF_SCR);
    scr[0] = 0.f;
    ((unsigned*)scr)[1] = 0u;
  }
  const int isY = id >= NSETPTS;
  const int pi = id & (NSETPTS - 1);
  const float* src = (isY ? y : yhat) + (size_t)pi * 3;
  const float x = src[0], yv = src[1], z = src[2];

  const unsigned short xh = f2bf(x),  yh = f2bf(yv), zh = f2bf(z);
  const unsigned short xl = f2bf(x - bf2f(xh));
  const unsigned short yl = f2bf(yv - bf2f(yh));
  const unsigned short zl = f2bf(z - bf2f(zh));
  const float sq = fmaf(x, x, fmaf(yv, yv, z * z));
  const unsigned short sh = f2bf(sq), sl = f2bf(sq - bf2f(sh));
  const unsigned short nxh = f2bf(-2.f * bf2f(xh)), nyh = f2bf(-2.f * bf2f(yh)),
                       nzh = f2bf(-2.f * bf2f(zh));
  const unsigned short nxl = f2bf(-2.f * bf2f(xl)), nyl = f2bf(-2.f * bf2f(yl)),
                       nzl = f2bf(-2.f * bf2f(zl));
  const unsigned short ONE = 0x3F80;

  const unsigned short av[16] = {xh, yh, zh, xh, yh, zh, xl, yl, zl,
                                 sh, sl, ONE, ONE, 0, 0, 0};
  const unsigned short bv[16] = {nxh, nyh, nzh, nxl, nyl, nzl, nxh, nyh, nzh,
                                 ONE, ONE, sh, sl, 0, 0, 0};
  uint4* Aout = (uint4*)(ws + (isY ? OFF_A_Y : OFF_A_YHAT)) + (size_t)pi * 2;
  uint4* Bout = (uint4*)(ws + (isY ? OFF_B_Y : OFF_B_YHAT)) + (size_t)pi * 2;
  Aout[0] = pack8(av);
  Aout[1] = pack8(av + 8);
  Bout[0] = pack8(bv);
  Bout[1] = pack8(bv + 8);
}

// Transposed MFMA: mfma(bv_lds, av_reg, 0) -> D reg-rows = m (b-points),
// lane-cols = n (a-points). Min over m = in-lane v_min3 fold of the 16 regs
// into one running scalar; single shfl_xor(32) + atomicMin at the end.
// Wave holds TWO n-frags (64 a-points) so each ds_read feeds 2 MFMAs.
__global__ __launch_bounds__(256, 2) void chamfer_min_kernel(
    unsigned char* __restrict__ ws) {
  const int bz = blockIdx.z, b = bz >> 1, dir = bz & 1;
  const uint4* Avec = (const uint4*)(ws + (dir ? OFF_A_Y : OFF_A_YHAT)) +
                      (size_t)b * NPTS * 2;
  const uint4* Bvec = (const uint4*)(ws + (dir ? OFF_B_YHAT : OFF_B_Y)) +
                      (size_t)b * NPTS * 2;
  unsigned* part = (unsigned*)(ws + OFF_PART);

  __shared__ uint4 bs[2][MCHUNK];  // [k-half][point], 32 KB
  const int m0 = blockIdx.y * MCHUNK;
  for (int i = threadIdx.x; i < MCHUNK; i += 256) {
    bs[0][i] = Bvec[(size_t)(m0 + i) * 2];
    bs[1][i] = Bvec[(size_t)(m0 + i) * 2 + 1];
  }

  const int lane = threadIdx.x & 63, wave = threadIdx.x >> 6;
  const int h = lane >> 5, c = lane & 31;
  const int n0 = blockIdx.x * 256 + wave * 64;
  uint4 ar0 = Avec[(size_t)(n0 + c) * 2 + h];
  uint4 ar1 = Avec[(size_t)(n0 + 32 + c) * 2 + h];
  asm("" : "+v"(ar0.x), "+v"(ar0.y), "+v"(ar0.z), "+v"(ar0.w),
           "+v"(ar1.x), "+v"(ar1.y), "+v"(ar1.z), "+v"(ar1.w));
  const bf16x8 a0 = __builtin_bit_cast(bf16x8, ar0);
  const bf16x8 a1 = __builtin_bit_cast(bf16x8, ar1);
  __syncthreads();

  float rm0 = 3.0e38f, rm1 = 3.0e38f;
  const f32x16 z = (f32x16)(0.0f);

  for (int t = 0; t < MCHUNK / 32; t += 2) {
    uint4 br0 = bs[h][t * 32 + c];
    uint4 br1 = bs[h][(t + 1) * 32 + c];
    asm("" : "+v"(br0.x), "+v"(br0.y), "+v"(br0.z), "+v"(br0.w),
             "+v"(br1.x), "+v"(br1.y), "+v"(br1.z), "+v"(br1.w));
    const bf16x8 b0 = __builtin_bit_cast(bf16x8, br0);
    const bf16x8 b1 = __builtin_bit_cast(bf16x8, br1);
    f32x16 p00 = __builtin_amdgcn_mfma_f32_32x32x16_bf16(b0, a0, z, 0, 0, 0);
    f32x16 p01 = __builtin_amdgcn_mfma_f32_32x32x16_bf16(b0, a1, z, 0, 0, 0);
    f32x16 p10 = __builtin_amdgcn_mfma_f32_32x32x16_bf16(b1, a0, z, 0, 0, 0);
    f32x16 p11 = __builtin_amdgcn_mfma_f32_32x32x16_bf16(b1, a1, z, 0, 0, 0);
#pragma unroll
    for (int r = 0; r < 16; r += 2) {
      rm0 = fminf(rm0, fminf(p00[r], p00[r + 1]));  // v_min3_f32
      rm0 = fminf(rm0, fminf(p10[r], p10[r + 1]));
      rm1 = fminf(rm1, fminf(p01[r], p01[r + 1]));
      rm1 = fminf(rm1, fminf(p11[r], p11[r + 1]));
    }
  }

  // merge the two k-halves' partial tiles... (halves hold different m-rows
  // of the SAME tile? no: halves hold same tile, regs+h decode all 32 rows)
  // rows covered in-lane: (r&3)+8*(r>>2)+4*h -> h=0 and h=1 cover disjoint
  // row sets; the shfl_xor(32) merges them AND broadcasts both frags.
  rm0 = fminf(rm0, __shfl_xor(rm0, 32));
  rm1 = fminf(rm1, __shfl_xor(rm1, 32));
  const float v = h ? rm1 : rm0;
  atomicMin(&part[bz * NPTS + n0 + (h << 5) + c], __float_as_uint(v));
}

// clamp + sum part[TOTALA] -> atomicAdd -> last block sqrt + store.
__global__ __launch_bounds__(256) void chamfer_reduce_kernel(
    unsigned char* __restrict__ ws, float* __restrict__ out) {
  const unsigned* part = (const unsigned*)(ws + OFF_PART);
  float* scr = (float*)(ws + OFF_SCR);
  const int j = blockIdx.x * 256 + threadIdx.x;  // 0..65535
  float s = fmaxf(__uint_as_float(part[j]), 0.f);
#pragma unroll
  for (int off = 32; off > 0; off >>= 1) s += __shfl_down(s, off, 64);
  __shared__ float p4[4];
  const int wave = threadIdx.x >> 6, lane = threadIdx.x & 63;
  if (lane == 0) p4[wave] = s;
  __syncthreads();
  if (threadIdx.x == 0) {
    atomicAdd(&scr[0], p4[0] + p4[1] + p4[2] + p4[3]);
    __threadfence();
    const unsigned ticket = atomicAdd(&((unsigned*)scr)[1], 1u);
    if (ticket == gridDim.x - 1) {
      __threadfence();
      const float total = atomicAdd(&scr[0], 0.f);  // atomic read
      out[0] = sqrtf(total * (1.0f / (float)TOTALA));
    }
  }
}

extern "C" void kernel_launch(void* const* d_in, const int* in_sizes, int n_in,
                              void* d_out, int out_size, void* d_ws, size_t ws_size,
                              hipStream_t stream) {
  const float* yhat = (const float*)d_in[0];
  const float* y    = (const float*)d_in[1];
  unsigned char* ws = (unsigned char*)d_ws;

  chamfer_prep_kernel<<<TOTALA / 256, 256, 0, stream>>>(yhat, y, ws);
  dim3 grid(NPTS / 256, NCH, 2 * BQ);
  chamfer_min_kernel<<<grid, 256, 0, stream>>>(ws);
  chamfer_reduce_kernel<<<256, 256, 0, stream>>>(ws, (float*)d_out);
}